// Round 16
// baseline (419.980 us; speedup 1.0000x reference)
//
#include <hip/hip_runtime.h>
#include <hip/hip_bf16.h>

// GCN: x[N,2] -> GCN(16) -> GCN(32) -> GCN(48) -> segmax pool [G,48] -> MLP -> [G,10]
//
// Aggregate in INPUT space (A_hat(HW) = (A_hat H)W): 2/16/32 ch per edge.
// g[i] = dis[i]*h[i];  (A_hat h)[d] = dis[d] * (sum_{e:dst=d} g[src] + g[d]).
// CSR via bucketed counting sort. Gather is CHANNEL-CHUNKED (8 ch/pass): the
// random-access array per pass is N*8*4 = 3.2MB < 4MB per-XCD L2 -> gathers
// become L2 hits after cold fill (12.8MB working set was only ~60% hit).
// g is stored chunk-major ([chunk][node][8]) by the pre kernels.
// MLP head: 4 graphs/block, weights in LDS. barr aliases h3 (~59MB workspace).

#define THREADS 256
#define NBSHIFT 7
#define NPB 128        // nodes per bucket = 1<<NBSHIFT
#define MAXNB 1024     // supports N <= 131072
#define SCAT_T 8192    // edges per block in bkt_scatter
#define SCAT_K 32      // edges per thread (SCAT_T / 256)

// ---- CSR build ----

__global__ void bkt_count(const int* __restrict__ dst, int* __restrict__ bktCnt,
                          int nE, int nb) {
    __shared__ int h[MAXNB];
    for (int i = threadIdx.x; i < nb; i += blockDim.x) h[i] = 0;
    __syncthreads();
    for (long e = blockIdx.x * blockDim.x + threadIdx.x; e < nE;
         e += (long)gridDim.x * blockDim.x)
        atomicAdd(&h[dst[e] >> NBSHIFT], 1);
    __syncthreads();
    for (int i = threadIdx.x; i < nb; i += blockDim.x)
        if (h[i]) atomicAdd(&bktCnt[i], h[i]);
}

__global__ void bkt_scan(const int* __restrict__ bktCnt, int* __restrict__ bktBase,
                         int* __restrict__ bktCursor, int nb) {
    __shared__ int sm[MAXNB];
    int t = threadIdx.x;
    int v = (t < nb) ? bktCnt[t] : 0;
    sm[t] = v;
    __syncthreads();
    for (int o = 1; o < MAXNB; o <<= 1) {
        int add = (t >= o) ? sm[t - o] : 0;
        __syncthreads();
        sm[t] += add;
        __syncthreads();
    }
    if (t < nb) {
        int b = sm[t] - v;  // exclusive
        bktBase[t] = b;
        bktCursor[t] = b;
    }
}

// packed word: src in bits[19:0] (N < 2^20), dstLow in bits[26:20]
__global__ void bkt_scatter(const int* __restrict__ src, const int* __restrict__ dst,
                            int* __restrict__ bktCursor, unsigned* __restrict__ barr,
                            int nE, int nb) {
    __shared__ int h[MAXNB];
    __shared__ int base[MAXNB];
    long t0 = (long)blockIdx.x * SCAT_T;
    for (int i = threadIdx.x; i < nb; i += blockDim.x) h[i] = 0;
    __syncthreads();
    unsigned pk[SCAT_K];
    int br[SCAT_K];
#pragma unroll
    for (int k = 0; k < SCAT_K; ++k) {
        long e = t0 + (long)k * 256 + threadIdx.x;
        if (e < nE) {
            int d = dst[e], s = src[e];
            int b = d >> NBSHIFT;
            int r = atomicAdd(&h[b], 1);           // rank within (block,bucket), < 8192
            pk[k] = (unsigned)s | ((unsigned)(d & (NPB - 1)) << 20);
            br[k] = (b << 13) | r;
        } else {
            br[k] = -1;
        }
    }
    __syncthreads();
    for (int i = threadIdx.x; i < nb; i += blockDim.x) {
        int c = h[i];
        base[i] = c ? atomicAdd(&bktCursor[i], c) : 0;
    }
    __syncthreads();
#pragma unroll
    for (int k = 0; k < SCAT_K; ++k) {
        if (br[k] >= 0) {
            int b = br[k] >> 13, r = br[k] & 8191;
            barr[(long)base[b] + r] = pk[k];
        }
    }
}

// per-bucket counting sort: emits col (sorted by dst), deg, rowstart
__global__ void bkt_sort(const int* __restrict__ bktBase, const int* __restrict__ bktCnt,
                         const unsigned* __restrict__ barr, int* __restrict__ col,
                         int* __restrict__ deg, int* __restrict__ rowstart, int n) {
    __shared__ int h[NPB], inc[NPB], c2[NPB];
    int b = blockIdx.x;
    int node0 = b << NBSHIFT;
    int nlocal = min(NPB, n - node0);
    int t = threadIdx.x;
    if (t < NPB) { h[t] = 0; c2[t] = 0; }
    __syncthreads();
    int base = bktBase[b], cnt = bktCnt[b];
    for (int i = t; i < cnt; i += blockDim.x)
        atomicAdd(&h[(barr[(long)base + i] >> 20) & (NPB - 1)], 1);
    __syncthreads();
    if (t < NPB) inc[t] = h[t];
    __syncthreads();
    for (int o = 1; o < NPB; o <<= 1) {
        int add = (t >= o && t < NPB) ? inc[t - o] : 0;
        __syncthreads();
        if (t < NPB) inc[t] += add;
        __syncthreads();
    }
    // inc = inclusive scan; exclusive = inc - h
    if (t < nlocal) {
        int node = node0 + t;
        deg[node] = h[t];
        rowstart[node] = base + inc[t] - h[t];
    }
    __syncthreads();
    for (int i = t; i < cnt; i += blockDim.x) {
        unsigned w = barr[(long)base + i];
        int dl = (w >> 20) & (NPB - 1);
        int r = atomicAdd(&c2[dl], 1);
        col[(long)base + inc[dl] - h[dl] + r] = (int)(w & 0xFFFFF);
    }
}

__global__ void dis_kernel(const int* __restrict__ deg, float* __restrict__ dis, int n) {
    int i = blockIdx.x * blockDim.x + threadIdx.x;
    if (i < n) dis[i] = 1.0f / sqrtf((float)(deg[i] + 1));  // +1 self loop
}

// ---- per-layer compute ----

__global__ void pre1_kernel(const float* __restrict__ x, const float* __restrict__ dis,
                            float* __restrict__ g, int n) {
    int i = blockIdx.x * blockDim.x + threadIdx.x;
    if (i >= n) return;
    float d = dis[i];
    float2 v = ((const float2*)x)[i];
    v.x *= d; v.y *= d;
    ((float2*)g)[i] = v;
}

// h = relu( (dis*accPrev) @ W + b ) ; g = dis*h, written CHUNK-MAJOR:
// g[(c>>3)*n*8 + i*8 + (c&7)]
template <int CIN, int COUT>
__global__ void pre_kernel(const float* __restrict__ accPrev, const float* __restrict__ dis,
                           const float* __restrict__ W, const float* __restrict__ b,
                           float* __restrict__ g, int n) {
    int i = blockIdx.x * blockDim.x + threadIdx.x;
    if (i >= n) return;
    float d = dis[i];
    float a[CIN];
#pragma unroll
    for (int k = 0; k < CIN; ++k) a[k] = d * accPrev[(long)i * CIN + k];
    float o[COUT];
#pragma unroll
    for (int c = 0; c < COUT; ++c) o[c] = b[c];
#pragma unroll
    for (int k = 0; k < CIN; ++k) {
        float ak = a[k];
#pragma unroll
        for (int c = 0; c < COUT; ++c) o[c] += ak * W[k * COUT + c];
    }
#pragma unroll
    for (int c = 0; c < COUT; ++c)
        g[((long)(c >> 3) * n + i) * 8 + (c & 7)] = d * fmaxf(o[c], 0.0f);
}

template <int CIN, int COUT>
__global__ void final_kernel(const float* __restrict__ accPrev, const float* __restrict__ dis,
                             const float* __restrict__ W, const float* __restrict__ b,
                             float* __restrict__ h, int n) {
    int i = blockIdx.x * blockDim.x + threadIdx.x;
    if (i >= n) return;
    float d = dis[i];
    float a[CIN];
#pragma unroll
    for (int k = 0; k < CIN; ++k) a[k] = d * accPrev[(long)i * CIN + k];
    float o[COUT];
#pragma unroll
    for (int c = 0; c < COUT; ++c) o[c] = b[c];
#pragma unroll
    for (int k = 0; k < CIN; ++k) {
        float ak = a[k];
#pragma unroll
        for (int c = 0; c < COUT; ++c) o[c] += ak * W[k * COUT + c];
    }
#pragma unroll
    for (int c = 0; c < COUT; ++c) h[(long)i * COUT + c] = fmaxf(o[c], 0.0f);
}

// scalar gather (CIN=2; g node-major, 800KB L2-resident)
template <int CIN>
__global__ void gather_kernel(const int* __restrict__ rowstart, const int* __restrict__ deg,
                              const int* __restrict__ col, const float* __restrict__ g,
                              float* __restrict__ acc, int n) {
    int gtid = blockIdx.x * blockDim.x + threadIdx.x;
    int node = gtid >> 6;
    int lane = threadIdx.x & 63;
    if (node >= n) return;
    constexpr int EPW = 64 / CIN;
    int c = lane % CIN;
    int es = lane / CIN;
    int base = rowstart[node];
    int dg = deg[node];
    float sum = 0.0f;
    for (int j = es; j < dg; j += EPW) {
        int s = col[base + j];
        sum += g[(long)s * CIN + c];
    }
#pragma unroll
    for (int m = CIN; m < 64; m <<= 1) sum += __shfl_xor(sum, m);
    if (lane < CIN) acc[(long)node * CIN + c] = g[(long)node * CIN + c] + sum;
}

// chunked gather: one 8-channel chunk (3.2MB array, fits per-XCD L2).
// 2 nodes per wave; per node: 2 float4-lanes x 16 edge-slots.
// acc written node-major [node][CIN] at float4 slot chunk*2+c4.
template <int CIN>
__global__ void gather8_kernel(const int* __restrict__ rowstart, const int* __restrict__ deg,
                               const int* __restrict__ col, const float* __restrict__ g,
                               float* __restrict__ acc, int n, int chunk) {
    int gtid = blockIdx.x * blockDim.x + threadIdx.x;
    int wave = gtid >> 6;
    int lane = threadIdx.x & 63;
    int node = wave * 2 + (lane >> 5);
    if (node >= n) return;
    int l = lane & 31;
    int c4 = l & 1;       // which float4 of the 8-ch chunk
    int es = l >> 1;      // edge slot 0..15
    int base = rowstart[node];
    int dg = deg[node];
    const float4* gc4 = (const float4*)(g + (size_t)chunk * n * 8);
    float4 sum = make_float4(0.f, 0.f, 0.f, 0.f);
    for (int j = es; j < dg; j += 16) {
        int s = col[base + j];
        float4 v = gc4[(long)s * 2 + c4];
        sum.x += v.x; sum.y += v.y; sum.z += v.z; sum.w += v.w;
    }
#pragma unroll
    for (int m = 2; m <= 16; m <<= 1) {  // reduce over es within 32-lane half
        sum.x += __shfl_xor(sum.x, m);
        sum.y += __shfl_xor(sum.y, m);
        sum.z += __shfl_xor(sum.z, m);
        sum.w += __shfl_xor(sum.w, m);
    }
    if (l < 2) {
        float4 self = gc4[(long)node * 2 + c4];
        float4 r = make_float4(self.x + sum.x, self.y + sum.y,
                               self.z + sum.z, self.w + sum.w);
        ((float4*)acc)[(long)node * (CIN / 4) + chunk * 2 + c4] = r;
    }
}

__global__ void pool_kernel(const float* __restrict__ h, const int* __restrict__ batch,
                            unsigned* __restrict__ pooled, int n) {
    const int C = 48, K = 16;
    int tid = blockIdx.x * blockDim.x + threadIdx.x;
    int chunk = tid / C, c = tid % C;
    int j0 = chunk * K;
    if (j0 >= n) return;
    int jend = min(j0 + K, n);
    int cur = batch[j0];
    float m = 0.0f;
    for (int j = j0; j < jend; ++j) {
        int gph = batch[j];
        if (gph != cur) {
            atomicMax(&pooled[cur * C + c], __float_as_uint(m));
            cur = gph;
            m = 0.0f;
        }
        m = fmaxf(m, h[(long)j * C + c]);
    }
    atomicMax(&pooled[cur * C + c], __float_as_uint(m));
}

// MLP head: 4 graphs per 256-thread block; Wl1/Wl2 staged in LDS.
__global__ void mlp_kernel(const unsigned* __restrict__ pooled, const float* __restrict__ Wl1,
                           const float* __restrict__ bl1, const float* __restrict__ Wl2,
                           const float* __restrict__ bl2, float* __restrict__ out, int G) {
    __shared__ float sW1[48 * 24];
    __shared__ float sW2[24 * 10];
    __shared__ float sp[4][48];
    __shared__ float sh[4][24];
    int t = threadIdx.x;
    int sub = t >> 6;      // graph slot 0..3
    int lane = t & 63;
    int g = blockIdx.x * 4 + sub;
    for (int i = t; i < 48 * 24; i += 256) sW1[i] = Wl1[i];
    for (int i = t; i < 24 * 10; i += 256) sW2[i] = Wl2[i];
    if (g < G && lane < 48) sp[sub][lane] = __uint_as_float(pooled[g * 48 + lane]);
    __syncthreads();
    if (g < G && lane < 24) {
        float a = bl1[lane];
#pragma unroll
        for (int k = 0; k < 48; ++k) a += sp[sub][k] * sW1[k * 24 + lane];
        sh[sub][lane] = fmaxf(a, 0.0f);
    }
    __syncthreads();
    if (g < G && lane < 10) {
        float a = bl2[lane];
#pragma unroll
        for (int j = 0; j < 24; ++j) a += sh[sub][j] * sW2[j * 10 + lane];
        out[g * 10 + lane] = a;
    }
}

static inline int cdiv(long a, int b) { return (int)((a + b - 1) / b); }

extern "C" void kernel_launch(void* const* d_in, const int* in_sizes, int n_in,
                              void* d_out, int out_size, void* d_ws, size_t ws_size,
                              hipStream_t stream) {
    const float* x = (const float*)d_in[0];
    const int* ei = (const int*)d_in[1];
    const int* batch = (const int*)d_in[2];
    const float* W1 = (const float*)d_in[3];
    const float* b1 = (const float*)d_in[4];
    const float* W2 = (const float*)d_in[5];
    const float* b2 = (const float*)d_in[6];
    const float* W3 = (const float*)d_in[7];
    const float* b3 = (const float*)d_in[8];
    const float* Wl1 = (const float*)d_in[9];
    const float* bl1 = (const float*)d_in[10];
    const float* Wl2 = (const float*)d_in[11];
    const float* bl2 = (const float*)d_in[12];
    float* out = (float*)d_out;

    const int N = in_sizes[0] / 2;
    const int E = in_sizes[1] / 2;
    const int G = out_size / 10;
    const int nb = cdiv(N, NPB);  // buckets; requires N <= 131072 (holds: N=100000)

    const int* src = ei;
    const int* dst = ei + E;

    // workspace layout (256B aligned), ~59MB total
    char* w = (char*)d_ws;
    size_t off = 0;
    auto alloc = [&](size_t bytes) {
        void* p = w + off;
        off = (off + bytes + 255) & ~(size_t)255;
        return p;
    };
    int* bktCnt = (int*)alloc((size_t)MAXNB * 4);
    int* bktBase = (int*)alloc((size_t)MAXNB * 4);
    int* bktCursor = (int*)alloc((size_t)MAXNB * 4);
    // barr (CSR staging, E*4) and h3 (final feats, N*48*4) have disjoint
    // lifetimes -> share one region sized for the larger.
    size_t shared_bytes = ((size_t)E * 4 > (size_t)N * 48 * 4) ? (size_t)E * 4
                                                               : (size_t)N * 48 * 4;
    void* shared_region = alloc(shared_bytes);
    unsigned* barr = (unsigned*)shared_region;
    float* h3 = (float*)shared_region;
    int* col = (int*)alloc((size_t)E * 4);
    int* deg = (int*)alloc((size_t)N * 4);
    float* dis = (float*)alloc((size_t)N * 4);
    int* rowstart = (int*)alloc((size_t)N * 4);
    float* g = (float*)alloc((size_t)N * 32 * 4);
    float* acc = (float*)alloc((size_t)N * 32 * 4);
    unsigned* pooled = (unsigned*)alloc((size_t)G * 48 * 4);
    (void)ws_size;

    hipMemsetAsync(bktCnt, 0, (size_t)MAXNB * 4, stream);
    hipMemsetAsync(pooled, 0, (size_t)G * 48 * 4, stream);

    // CSR build: bucketed counting sort by dst
    bkt_count<<<512, THREADS, 0, stream>>>(dst, bktCnt, E, nb);
    bkt_scan<<<1, MAXNB, 0, stream>>>(bktCnt, bktBase, bktCursor, nb);
    bkt_scatter<<<cdiv(E, SCAT_T), THREADS, 0, stream>>>(src, dst, bktCursor, barr, E, nb);
    bkt_sort<<<nb, THREADS, 0, stream>>>(bktBase, bktCnt, barr, col, deg, rowstart, N);
    dis_kernel<<<cdiv(N, THREADS), THREADS, 0, stream>>>(deg, dis, N);

    // Layer 1: aggregate x-space (2 ch, node-major, L2-resident)
    pre1_kernel<<<cdiv(N, THREADS), THREADS, 0, stream>>>(x, dis, g, N);
    gather_kernel<2><<<cdiv((long)N * 64, THREADS), THREADS, 0, stream>>>(
        rowstart, deg, col, g, acc, N);

    // Layer 2: h1 = relu((dis*acc)@W1+b1); aggregate 16 ch in 2 chunked passes
    pre_kernel<2, 16><<<cdiv(N, THREADS), THREADS, 0, stream>>>(acc, dis, W1, b1, g, N);
    for (int ch = 0; ch < 2; ++ch)
        gather8_kernel<16><<<cdiv((long)N * 32, THREADS), THREADS, 0, stream>>>(
            rowstart, deg, col, g, acc, N, ch);

    // Layer 3: h2 = relu((dis*acc)@W2+b2); aggregate 32 ch in 4 chunked passes
    pre_kernel<16, 32><<<cdiv(N, THREADS), THREADS, 0, stream>>>(acc, dis, W2, b2, g, N);
    for (int ch = 0; ch < 4; ++ch)
        gather8_kernel<32><<<cdiv((long)N * 32, THREADS), THREADS, 0, stream>>>(
            rowstart, deg, col, g, acc, N, ch);

    // Final node features: h3 = relu((dis*acc)@W3+b3)  [N,48]  (barr is dead now)
    final_kernel<32, 48><<<cdiv(N, THREADS), THREADS, 0, stream>>>(acc, dis, W3, b3, h3, N);

    // Segment-max pool (batch sorted)
    pool_kernel<<<cdiv((long)cdiv(N, 16) * 48, THREADS), THREADS, 0, stream>>>(h3, batch, pooled, N);

    // MLP head: 4 graphs/block
    mlp_kernel<<<cdiv(G, 4), THREADS, 0, stream>>>(pooled, Wl1, bl1, Wl2, bl2, out, G);
}

// Round 18
// 372.240 us; speedup vs baseline: 1.1282x; 1.1282x over previous
//
#include <hip/hip_runtime.h>
#include <hip/hip_bf16.h>

// GCN: x[N,2] -> GCN(16) -> GCN(32) -> GCN(48) -> segmax pool [G,48] -> MLP -> [G,10]
//
// Aggregate in INPUT space (A_hat(HW) = (A_hat H)W): 2/16/32 ch per edge.
// g[i] = dis[i]*h[i];  (A_hat h)[d] = dis[d] * (sum_{e:dst=d} g[src] + g[d]).
// CSR via bucketed counting sort. Monolithic float4 gather (channel-chunking
// REGRESSED: 374->420us; gather is LLC-latency-bound, not L2-capacity-bound).
// bkt_scatter: 1024-thr blocks (was 10.7% occupancy at 256thr/391blk).
// MLP head: 4 graphs/block, weights in LDS. barr aliases h3 (~59MB workspace).

#define THREADS 256
#define NBSHIFT 7
#define NPB 128        // nodes per bucket = 1<<NBSHIFT
#define MAXNB 1024     // supports N <= 131072
#define SCAT_T 8192    // edges per block in bkt_scatter
#define SCAT_B 1024    // threads per block in bkt_scatter
#define SCAT_K 8       // edges per thread (SCAT_T / SCAT_B)

// ---- CSR build ----

__global__ void bkt_count(const int* __restrict__ dst, int* __restrict__ bktCnt,
                          int nE, int nb) {
    __shared__ int h[MAXNB];
    for (int i = threadIdx.x; i < nb; i += blockDim.x) h[i] = 0;
    __syncthreads();
    for (long e = blockIdx.x * blockDim.x + threadIdx.x; e < nE;
         e += (long)gridDim.x * blockDim.x)
        atomicAdd(&h[dst[e] >> NBSHIFT], 1);
    __syncthreads();
    for (int i = threadIdx.x; i < nb; i += blockDim.x)
        if (h[i]) atomicAdd(&bktCnt[i], h[i]);
}

__global__ void bkt_scan(const int* __restrict__ bktCnt, int* __restrict__ bktBase,
                         int* __restrict__ bktCursor, int nb) {
    __shared__ int sm[MAXNB];
    int t = threadIdx.x;
    int v = (t < nb) ? bktCnt[t] : 0;
    sm[t] = v;
    __syncthreads();
    for (int o = 1; o < MAXNB; o <<= 1) {
        int add = (t >= o) ? sm[t - o] : 0;
        __syncthreads();
        sm[t] += add;
        __syncthreads();
    }
    if (t < nb) {
        int b = sm[t] - v;  // exclusive
        bktBase[t] = b;
        bktCursor[t] = b;
    }
}

// packed word: src in bits[19:0] (N < 2^20), dstLow in bits[26:20]
__global__ void bkt_scatter(const int* __restrict__ src, const int* __restrict__ dst,
                            int* __restrict__ bktCursor, unsigned* __restrict__ barr,
                            int nE, int nb) {
    __shared__ int h[MAXNB];
    __shared__ int base[MAXNB];
    long t0 = (long)blockIdx.x * SCAT_T;
    for (int i = threadIdx.x; i < nb; i += blockDim.x) h[i] = 0;
    __syncthreads();
    unsigned pk[SCAT_K];
    int br[SCAT_K];
#pragma unroll
    for (int k = 0; k < SCAT_K; ++k) {
        long e = t0 + (long)k * SCAT_B + threadIdx.x;
        if (e < nE) {
            int d = dst[e], s = src[e];
            int b = d >> NBSHIFT;
            int r = atomicAdd(&h[b], 1);           // rank within (block,bucket), < 8192
            pk[k] = (unsigned)s | ((unsigned)(d & (NPB - 1)) << 20);
            br[k] = (b << 13) | r;
        } else {
            br[k] = -1;
        }
    }
    __syncthreads();
    for (int i = threadIdx.x; i < nb; i += blockDim.x) {
        int c = h[i];
        base[i] = c ? atomicAdd(&bktCursor[i], c) : 0;
    }
    __syncthreads();
#pragma unroll
    for (int k = 0; k < SCAT_K; ++k) {
        if (br[k] >= 0) {
            int b = br[k] >> 13, r = br[k] & 8191;
            barr[(long)base[b] + r] = pk[k];
        }
    }
}

// per-bucket counting sort: emits col (sorted by dst), deg, rowstart
__global__ void bkt_sort(const int* __restrict__ bktBase, const int* __restrict__ bktCnt,
                         const unsigned* __restrict__ barr, int* __restrict__ col,
                         int* __restrict__ deg, int* __restrict__ rowstart, int n) {
    __shared__ int h[NPB], inc[NPB], c2[NPB];
    int b = blockIdx.x;
    int node0 = b << NBSHIFT;
    int nlocal = min(NPB, n - node0);
    int t = threadIdx.x;
    if (t < NPB) { h[t] = 0; c2[t] = 0; }
    __syncthreads();
    int base = bktBase[b], cnt = bktCnt[b];
    for (int i = t; i < cnt; i += blockDim.x)
        atomicAdd(&h[(barr[(long)base + i] >> 20) & (NPB - 1)], 1);
    __syncthreads();
    if (t < NPB) inc[t] = h[t];
    __syncthreads();
    for (int o = 1; o < NPB; o <<= 1) {
        int add = (t >= o && t < NPB) ? inc[t - o] : 0;
        __syncthreads();
        if (t < NPB) inc[t] += add;
        __syncthreads();
    }
    // inc = inclusive scan; exclusive = inc - h
    if (t < nlocal) {
        int node = node0 + t;
        deg[node] = h[t];
        rowstart[node] = base + inc[t] - h[t];
    }
    __syncthreads();
    for (int i = t; i < cnt; i += blockDim.x) {
        unsigned w = barr[(long)base + i];
        int dl = (w >> 20) & (NPB - 1);
        int r = atomicAdd(&c2[dl], 1);
        col[(long)base + inc[dl] - h[dl] + r] = (int)(w & 0xFFFFF);
    }
}

__global__ void dis_kernel(const int* __restrict__ deg, float* __restrict__ dis, int n) {
    int i = blockIdx.x * blockDim.x + threadIdx.x;
    if (i < n) dis[i] = 1.0f / sqrtf((float)(deg[i] + 1));  // +1 self loop
}

// ---- per-layer compute ----

__global__ void pre1_kernel(const float* __restrict__ x, const float* __restrict__ dis,
                            float* __restrict__ g, int n) {
    int i = blockIdx.x * blockDim.x + threadIdx.x;
    if (i >= n) return;
    float d = dis[i];
    float2 v = ((const float2*)x)[i];
    v.x *= d; v.y *= d;
    ((float2*)g)[i] = v;
}

// h = relu( (dis*accPrev) @ W + b ) ; g = dis*h (node-major)
template <int CIN, int COUT>
__global__ void pre_kernel(const float* __restrict__ accPrev, const float* __restrict__ dis,
                           const float* __restrict__ W, const float* __restrict__ b,
                           float* __restrict__ g, int n) {
    int i = blockIdx.x * blockDim.x + threadIdx.x;
    if (i >= n) return;
    float d = dis[i];
    float a[CIN];
#pragma unroll
    for (int k = 0; k < CIN; ++k) a[k] = d * accPrev[(long)i * CIN + k];
    float o[COUT];
#pragma unroll
    for (int c = 0; c < COUT; ++c) o[c] = b[c];
#pragma unroll
    for (int k = 0; k < CIN; ++k) {
        float ak = a[k];
#pragma unroll
        for (int c = 0; c < COUT; ++c) o[c] += ak * W[k * COUT + c];
    }
#pragma unroll
    for (int c = 0; c < COUT; ++c) g[(long)i * COUT + c] = d * fmaxf(o[c], 0.0f);
}

template <int CIN, int COUT>
__global__ void final_kernel(const float* __restrict__ accPrev, const float* __restrict__ dis,
                             const float* __restrict__ W, const float* __restrict__ b,
                             float* __restrict__ h, int n) {
    int i = blockIdx.x * blockDim.x + threadIdx.x;
    if (i >= n) return;
    float d = dis[i];
    float a[CIN];
#pragma unroll
    for (int k = 0; k < CIN; ++k) a[k] = d * accPrev[(long)i * CIN + k];
    float o[COUT];
#pragma unroll
    for (int c = 0; c < COUT; ++c) o[c] = b[c];
#pragma unroll
    for (int k = 0; k < CIN; ++k) {
        float ak = a[k];
#pragma unroll
        for (int c = 0; c < COUT; ++c) o[c] += ak * W[k * COUT + c];
    }
#pragma unroll
    for (int c = 0; c < COUT; ++c) h[(long)i * COUT + c] = fmaxf(o[c], 0.0f);
}

// scalar gather (CIN=2; g is 800KB, L2-resident)
template <int CIN>
__global__ void gather_kernel(const int* __restrict__ rowstart, const int* __restrict__ deg,
                              const int* __restrict__ col, const float* __restrict__ g,
                              float* __restrict__ acc, int n) {
    int gtid = blockIdx.x * blockDim.x + threadIdx.x;
    int node = gtid >> 6;
    int lane = threadIdx.x & 63;
    if (node >= n) return;
    constexpr int EPW = 64 / CIN;
    int c = lane % CIN;
    int es = lane / CIN;
    int base = rowstart[node];
    int dg = deg[node];
    float sum = 0.0f;
    for (int j = es; j < dg; j += EPW) {
        int s = col[base + j];
        sum += g[(long)s * CIN + c];
    }
#pragma unroll
    for (int m = CIN; m < 64; m <<= 1) sum += __shfl_xor(sum, m);
    if (lane < CIN) acc[(long)node * CIN + c] = g[(long)node * CIN + c] + sum;
}

// float4 gather (CIN in {16,32}): CIN/4 lanes per edge, 64/(CIN/4) edges in
// flight per wave.
template <int CIN>
__global__ void gather4_kernel(const int* __restrict__ rowstart, const int* __restrict__ deg,
                               const int* __restrict__ col, const float* __restrict__ g,
                               float* __restrict__ acc, int n) {
    constexpr int LPE = CIN / 4;   // lanes per edge
    constexpr int EPW = 64 / LPE;  // edges in flight
    int gtid = blockIdx.x * blockDim.x + threadIdx.x;
    int node = gtid >> 6;
    int lane = threadIdx.x & 63;
    if (node >= n) return;
    int c4 = lane & (LPE - 1);
    int es = lane / LPE;
    int base = rowstart[node];
    int dg = deg[node];
    float4 sum = make_float4(0.f, 0.f, 0.f, 0.f);
    for (int j = es; j < dg; j += EPW) {
        int s = col[base + j];
        float4 v = ((const float4*)g)[(long)s * LPE + c4];
        sum.x += v.x; sum.y += v.y; sum.z += v.z; sum.w += v.w;
    }
#pragma unroll
    for (int m = LPE; m < 64; m <<= 1) {
        sum.x += __shfl_xor(sum.x, m);
        sum.y += __shfl_xor(sum.y, m);
        sum.z += __shfl_xor(sum.z, m);
        sum.w += __shfl_xor(sum.w, m);
    }
    if (lane < LPE) {
        float4 self = ((const float4*)g)[(long)node * LPE + c4];
        float4 r = make_float4(self.x + sum.x, self.y + sum.y,
                               self.z + sum.z, self.w + sum.w);
        ((float4*)acc)[(long)node * LPE + c4] = r;
    }
}

__global__ void pool_kernel(const float* __restrict__ h, const int* __restrict__ batch,
                            unsigned* __restrict__ pooled, int n) {
    const int C = 48, K = 16;
    int tid = blockIdx.x * blockDim.x + threadIdx.x;
    int chunk = tid / C, c = tid % C;
    int j0 = chunk * K;
    if (j0 >= n) return;
    int jend = min(j0 + K, n);
    int cur = batch[j0];
    float m = 0.0f;
    for (int j = j0; j < jend; ++j) {
        int gph = batch[j];
        if (gph != cur) {
            atomicMax(&pooled[cur * C + c], __float_as_uint(m));
            cur = gph;
            m = 0.0f;
        }
        m = fmaxf(m, h[(long)j * C + c]);
    }
    atomicMax(&pooled[cur * C + c], __float_as_uint(m));
}

// MLP head: 4 graphs per 256-thread block; Wl1/Wl2 staged in LDS.
__global__ void mlp_kernel(const unsigned* __restrict__ pooled, const float* __restrict__ Wl1,
                           const float* __restrict__ bl1, const float* __restrict__ Wl2,
                           const float* __restrict__ bl2, float* __restrict__ out, int G) {
    __shared__ float sW1[48 * 24];
    __shared__ float sW2[24 * 10];
    __shared__ float sp[4][48];
    __shared__ float sh[4][24];
    int t = threadIdx.x;
    int sub = t >> 6;      // graph slot 0..3
    int lane = t & 63;
    int g = blockIdx.x * 4 + sub;
    for (int i = t; i < 48 * 24; i += 256) sW1[i] = Wl1[i];
    for (int i = t; i < 24 * 10; i += 256) sW2[i] = Wl2[i];
    if (g < G && lane < 48) sp[sub][lane] = __uint_as_float(pooled[g * 48 + lane]);
    __syncthreads();
    if (g < G && lane < 24) {
        float a = bl1[lane];
#pragma unroll
        for (int k = 0; k < 48; ++k) a += sp[sub][k] * sW1[k * 24 + lane];
        sh[sub][lane] = fmaxf(a, 0.0f);
    }
    __syncthreads();
    if (g < G && lane < 10) {
        float a = bl2[lane];
#pragma unroll
        for (int j = 0; j < 24; ++j) a += sh[sub][j] * sW2[j * 10 + lane];
        out[g * 10 + lane] = a;
    }
}

static inline int cdiv(long a, int b) { return (int)((a + b - 1) / b); }

extern "C" void kernel_launch(void* const* d_in, const int* in_sizes, int n_in,
                              void* d_out, int out_size, void* d_ws, size_t ws_size,
                              hipStream_t stream) {
    const float* x = (const float*)d_in[0];
    const int* ei = (const int*)d_in[1];
    const int* batch = (const int*)d_in[2];
    const float* W1 = (const float*)d_in[3];
    const float* b1 = (const float*)d_in[4];
    const float* W2 = (const float*)d_in[5];
    const float* b2 = (const float*)d_in[6];
    const float* W3 = (const float*)d_in[7];
    const float* b3 = (const float*)d_in[8];
    const float* Wl1 = (const float*)d_in[9];
    const float* bl1 = (const float*)d_in[10];
    const float* Wl2 = (const float*)d_in[11];
    const float* bl2 = (const float*)d_in[12];
    float* out = (float*)d_out;

    const int N = in_sizes[0] / 2;
    const int E = in_sizes[1] / 2;
    const int G = out_size / 10;
    const int nb = cdiv(N, NPB);  // buckets; requires N <= 131072 (holds: N=100000)

    const int* src = ei;
    const int* dst = ei + E;

    // workspace layout (256B aligned), ~59MB total
    char* w = (char*)d_ws;
    size_t off = 0;
    auto alloc = [&](size_t bytes) {
        void* p = w + off;
        off = (off + bytes + 255) & ~(size_t)255;
        return p;
    };
    int* bktCnt = (int*)alloc((size_t)MAXNB * 4);
    int* bktBase = (int*)alloc((size_t)MAXNB * 4);
    int* bktCursor = (int*)alloc((size_t)MAXNB * 4);
    // barr (CSR staging, E*4) and h3 (final feats, N*48*4) have disjoint
    // lifetimes -> share one region sized for the larger.
    size_t shared_bytes = ((size_t)E * 4 > (size_t)N * 48 * 4) ? (size_t)E * 4
                                                               : (size_t)N * 48 * 4;
    void* shared_region = alloc(shared_bytes);
    unsigned* barr = (unsigned*)shared_region;
    float* h3 = (float*)shared_region;
    int* col = (int*)alloc((size_t)E * 4);
    int* deg = (int*)alloc((size_t)N * 4);
    float* dis = (float*)alloc((size_t)N * 4);
    int* rowstart = (int*)alloc((size_t)N * 4);
    float* g = (float*)alloc((size_t)N * 32 * 4);
    float* acc = (float*)alloc((size_t)N * 32 * 4);
    unsigned* pooled = (unsigned*)alloc((size_t)G * 48 * 4);
    (void)ws_size;

    hipMemsetAsync(bktCnt, 0, (size_t)MAXNB * 4, stream);
    hipMemsetAsync(pooled, 0, (size_t)G * 48 * 4, stream);

    // CSR build: bucketed counting sort by dst
    bkt_count<<<1024, THREADS, 0, stream>>>(dst, bktCnt, E, nb);
    bkt_scan<<<1, MAXNB, 0, stream>>>(bktCnt, bktBase, bktCursor, nb);
    bkt_scatter<<<cdiv(E, SCAT_T), SCAT_B, 0, stream>>>(src, dst, bktCursor, barr, E, nb);
    bkt_sort<<<nb, 512, 0, stream>>>(bktBase, bktCnt, barr, col, deg, rowstart, N);
    dis_kernel<<<cdiv(N, THREADS), THREADS, 0, stream>>>(deg, dis, N);

    // Layer 1: aggregate x-space (2 ch)
    pre1_kernel<<<cdiv(N, THREADS), THREADS, 0, stream>>>(x, dis, g, N);
    gather_kernel<2><<<cdiv((long)N * 64, THREADS), THREADS, 0, stream>>>(
        rowstart, deg, col, g, acc, N);

    // Layer 2: h1 = relu((dis*acc)@W1+b1); aggregate 16 ch
    pre_kernel<2, 16><<<cdiv(N, THREADS), THREADS, 0, stream>>>(acc, dis, W1, b1, g, N);
    gather4_kernel<16><<<cdiv((long)N * 64, THREADS), THREADS, 0, stream>>>(
        rowstart, deg, col, g, acc, N);

    // Layer 3: h2 = relu((dis*acc)@W2+b2); aggregate 32 ch
    pre_kernel<16, 32><<<cdiv(N, THREADS), THREADS, 0, stream>>>(acc, dis, W2, b2, g, N);
    gather4_kernel<32><<<cdiv((long)N * 64, THREADS), THREADS, 0, stream>>>(
        rowstart, deg, col, g, acc, N);

    // Final node features: h3 = relu((dis*acc)@W3+b3)  [N,48]  (barr is dead now)
    final_kernel<32, 48><<<cdiv(N, THREADS), THREADS, 0, stream>>>(acc, dis, W3, b3, h3, N);

    // Segment-max pool (batch sorted)
    pool_kernel<<<cdiv((long)cdiv(N, 16) * 48, THREADS), THREADS, 0, stream>>>(h3, batch, pooled, N);

    // MLP head: 4 graphs/block
    mlp_kernel<<<cdiv(G, 4), THREADS, 0, stream>>>(pooled, Wl1, bl1, Wl2, bl2, out, G);
}